// Round 1
// baseline (374.631 us; speedup 1.0000x reference)
//
#include <hip/hip_runtime.h>
#include <cstdint>

// Shapes (fixed by reference): b=4,h=8 -> BH=32 heads; n=2048; nc=1024; d=K=512.
#define NC    1024
#define D     512
#define KTOT  512
#define MTOT  32768       // BH * NC
#define BK    64

typedef short  short8  __attribute__((ext_vector_type(8)));   // 8 x bf16
typedef float  floatx4 __attribute__((ext_vector_type(4)));

__device__ inline void gl2lds16(const void* gptr, void* lptr) {
  __builtin_amdgcn_global_load_lds(
      (const __attribute__((address_space(1))) void*)gptr,
      (__attribute__((address_space(3))) void*)lptr,
      16, 0, 0);
}

__device__ inline unsigned short f2bf_rne(float f) {
  union { float f; unsigned u; } x; x.f = f;
  unsigned r = x.u + 0x7fffu + ((x.u >> 16) & 1u);
  return (unsigned short)(r >> 16);
}

__global__ __launch_bounds__(256) void cvt_f32_bf16(
    const float* __restrict__ src, unsigned short* __restrict__ dst, int n4) {
  int i = blockIdx.x * 256 + threadIdx.x;
  if (i >= n4) return;
  float4 v = ((const float4*)src)[i];
  ushort4 o;
  o.x = f2bf_rne(v.x); o.y = f2bf_rne(v.y);
  o.z = f2bf_rne(v.z); o.w = f2bf_rne(v.w);
  ((ushort4*)dst)[i] = o;
}

// Fused kernel: per workgroup, A rows [r0, r0+128] (129 rows, extra row for the
// P2 shift), dout cols [n0, n0+64). Three acc groups:
//   P0[j]  = u_j . W0^T,  P1[j] = u_j . W1^T,  P2s[j] = u_{j+1} . W2^T
// (block-2 MFMAs read A fragments at row+1; extra staged row zeroed at head
//  boundaries). Epilogue is then lane-local.
__global__ __launch_bounds__(256, 2) void fused_uncompress_gemm(
    const unsigned short* __restrict__ Ub,   // (32768, 512) bf16
    const unsigned short* __restrict__ Wb,   // (512, 1536) bf16, row-major
    const float* __restrict__ U32,           // (32768, 512) f32
    const float* __restrict__ LQ,            // (32, 2048, 512) f32
    const float* __restrict__ bias,          // (512) f32
    float* __restrict__ out)                 // (32, 2048, 512) f32
{
  // LDS: A = 129 rows x 64 bf16 (128 B/row), B = 192 rows x 64 bf16.
  // XOR-swizzled 16B chunks: slot s of row r holds global chunk (s ^ (r&7)).
  __shared__ __attribute__((aligned(16))) unsigned char smem[129*128 + 192*128];
  unsigned char* smemA = smem;
  unsigned char* smemB = smem + 129*128;

  const int tileM = blockIdx.x >> 3;
  const int tileN = blockIdx.x & 7;
  const int r0 = tileM * 128;
  const int n0 = tileN * 64;
  const int tid  = threadIdx.x;
  const int wv   = tid >> 6;
  const int ln   = tid & 63;
  const int quad = ln >> 4;
  const int am   = ln & 15;

  floatx4 acc[2][12];
  #pragma unroll
  for (int rt = 0; rt < 2; ++rt)
    #pragma unroll
    for (int ct = 0; ct < 12; ++ct)
      acc[rt][ct] = floatx4{0.f, 0.f, 0.f, 0.f};

  const bool zeroExtra = (((r0 + 128) & (NC - 1)) == 0);  // head boundary

  for (int kc = 0; kc < KTOT / BK; ++kc) {
    const int k0 = kc * BK;

    // ---- stage A rows 0..127 (wave wv: rows [wv*32, wv*32+32), 4 instrs x 8 rows)
    #pragma unroll
    for (int i = 0; i < 4; ++i) {
      int row = wv * 32 + i * 8 + (ln >> 3);
      int s   = ln & 7;
      int kch = s ^ (row & 7);
      const unsigned short* g = Ub + (size_t)(r0 + row) * KTOT + k0 + kch * 8;
      gl2lds16(g, smemA + (wv * 32 + i * 8) * 128);   // wave-uniform LDS base
    }
    // ---- stage A row 128 (row&7==0 -> identity swizzle)
    if (wv == 0 && ln < 8) {
      if (zeroExtra) {
        *(float4*)(smemA + 128 * 128 + ln * 16) = make_float4(0.f, 0.f, 0.f, 0.f);
      } else {
        const unsigned short* g = Ub + (size_t)(r0 + 128) * KTOT + k0 + ln * 8;
        gl2lds16(g, smemA + 128 * 128);
      }
    }
    // ---- stage B: rho = beta*64 + nl, beta in 0..2, nl in 0..63
    #pragma unroll
    for (int i = 0; i < 6; ++i) {
      int rho = wv * 48 + i * 8 + (ln >> 3);
      int s   = ln & 7;
      int kch = s ^ (rho & 7);
      int beta = rho >> 6;
      int nl   = rho & 63;
      const unsigned short* g =
          Wb + (size_t)(n0 + nl) * 1536 + beta * 512 + k0 + kch * 8;
      gl2lds16(g, smemB + (wv * 48 + i * 8) * 128);
    }
    __syncthreads();   // drains vmcnt(0) (global_load_lds) + lgkmcnt

    // ---- compute: wave wv owns rows [wv*32, wv*32+32), all 192 acc cols
    #pragma unroll
    for (int ks = 0; ks < 2; ++ks) {
      short8 a0[2], a1[2];
      #pragma unroll
      for (int rt = 0; rt < 2; ++rt) {
        int row  = wv * 32 + rt * 16 + am;
        int sl   = (ks * 4 + quad) ^ (row & 7);
        a0[rt] = *(const short8*)(smemA + row * 128 + sl * 16);
        int row1 = row + 1;
        int sl1  = (ks * 4 + quad) ^ (row1 & 7);
        a1[rt] = *(const short8*)(smemA + row1 * 128 + sl1 * 16);
      }
      #pragma unroll
      for (int ct = 0; ct < 12; ++ct) {
        int beta = ct >> 2;
        int nl   = (ct & 3) * 16 + am;
        int rho  = beta * 64 + nl;
        int sl   = (ks * 4 + quad) ^ (nl & 7);
        short8 b = *(const short8*)(smemB + rho * 128 + sl * 16);
        #pragma unroll
        for (int rt = 0; rt < 2; ++rt) {
          acc[rt][ct] = __builtin_amdgcn_mfma_f32_16x16x32_bf16(
              (beta == 2) ? a1[rt] : a0[rt], b, acc[rt][ct], 0, 0, 0);
        }
      }
    }
    __syncthreads();   // protect LDS before next stage
  }

  // ---- epilogue: C/D map col=lane&15, row=quad*4+reg (verified m89/m91)
  const float inv3 = 1.0f / 3.0f;
  #pragma unroll
  for (int dt = 0; dt < 4; ++dt) {
    int col = n0 + dt * 16 + am;
    float bv = bias[col];
    #pragma unroll
    for (int rt = 0; rt < 2; ++rt) {
      #pragma unroll
      for (int r = 0; r < 4; ++r) {
        int jl = wv * 32 + rt * 16 + quad * 4 + r;
        int j  = r0 + jl;
        int head = j >> 10;          // / NC
        int jn   = j & (NC - 1);
        size_t ob = ((size_t)head * 2048 + 2 * jn) * D + col;
        float p0 = acc[rt][dt][r];
        float p1 = acc[rt][4 + dt][r];
        float p2 = acc[rt][8 + dt][r];
        float uj  = U32[(size_t)j * D + col];
        float uj1 = (jn == NC - 1) ? 0.f : U32[(size_t)(j + 1) * D + col];
        float e = fmaxf(p1 + bv, 0.f);
        float o = fmaxf(p0 + p2 + bv, 0.f);
        out[ob]     = LQ[ob]     + e + uj * inv3;
        out[ob + D] = LQ[ob + D] + o + (uj + uj1) * inv3;
      }
    }
  }
}

extern "C" void kernel_launch(void* const* d_in, const int* in_sizes, int n_in,
                              void* d_out, int out_size, void* d_ws, size_t ws_size,
                              hipStream_t stream) {
  const float* LQ   = (const float*)d_in[0];   // (4,8,2048,512)
  const float* U32  = (const float*)d_in[1];   // (4,8,1024,512)
  const float* W    = (const float*)d_in[2];   // (512, 1536)
  const float* bias = (const float*)d_in[3];   // (512)
  // d_in[4] = i (unused; dropout p=0)
  float* out = (float*)d_out;

  unsigned short* Ub = (unsigned short*)d_ws;                         // 33.5 MB
  unsigned short* Wb = (unsigned short*)((char*)d_ws + (size_t)MTOT * KTOT * 2);

  const int n4U = MTOT * KTOT / 4;     // 4,194,304
  const int n4W = 512 * 1536 / 4;      // 196,608
  cvt_f32_bf16<<<(n4U + 255) / 256, 256, 0, stream>>>(U32, Ub, n4U);
  cvt_f32_bf16<<<(n4W + 255) / 256, 256, 0, stream>>>(W, Wb, n4W);

  // 256 M-tiles x 8 N-tiles; consecutive blocks share an M-tile (A reuse in L2)
  fused_uncompress_gemm<<<dim3(2048), dim3(256), 0, stream>>>(
      Ub, Wb, U32, LQ, bias, out);
}